// Round 7
// baseline (209.951 us; speedup 1.0000x reference)
//
#include <hip/hip_runtime.h>

// Problem constants (fixed by setup_inputs in the reference)
#define S_SPK 2
#define B_BATCH 4
#define M_MIC 4
#define W_TAP 3
#define F_FREQ 257
#define T_TIME 512
#define C_CH 4
#define FT (F_FREQ * T_TIME)      // 131584

#define NBLK_X 65                 // ceil(F/4): 4 f per block, 1 per wave
#define NBLK_Y 8                  // S*B
#define NSLOT (NBLK_X * NBLK_Y)   // 520 partial slots

// 4-byte-aligned vector types: mix window loads are only dword-aligned.
typedef float float4u __attribute__((ext_vector_type(4), aligned(4)));
typedef float float2a __attribute__((ext_vector_type(2), aligned(8)));

// ws layout: float partial[NSLOT][2]
//
// Rounds 4-6 lesson: per-wave MLP (reg-batch / 2-row / LDS-direct) is NOT the
// constraint - all land ~67us main. Theory: ~27K concurrent 1KB mask streams
// destroy DRAM locality (effective ~2.2 TB/s vs fill kernel's 6.9 TB/s).
// This round: one wave owns a full (sb,f) T-row and walks it in 4 sequential
// 128-t chunks -> each of its 12 mask streams is a contiguous 4KB run, with
// 1-chunk-ahead prefetch (double-buffered registers, unrolled -> static idx).

__global__ __launch_bounds__(256) void pit_main_kernel(
    const float* __restrict__ masks,   // [S,B,M,W,F,T,2]
    const float* __restrict__ mixr,    // [S,B,M,F,T]
    const float* __restrict__ mixi,    // [S,B,M,F,T]
    const float* __restrict__ tgtr,    // [S,B,C,F,T] (use c=0)
    const float* __restrict__ tgti,    // [S,B,C,F,T]
    float* __restrict__ ws)
{
    const int sb   = blockIdx.y;            // so*B + b
    const int b    = sb & 3;
    const int wave = threadIdx.x >> 6;
    const int lane = threadIdx.x & 63;

    const int f    = blockIdx.x * 4 + wave; // one f-row per wave
    const int fc   = (f < F_FREQ) ? f : (F_FREQ - 1);   // clamped (no OOB)
    const float vf = (f < F_FREQ) ? 1.0f : 0.0f;        // validity flag

    const long rowBase = (long)fc * T_TIME;
    const long mixSB   = (long)sb * M_MIC * FT + rowBase;

    // mask base for this (sb, f): 12 (m,w) streams, stride F*T*2 floats (~1MB);
    // within a stream, chunk c advances by 256 floats (1KB) -> 4KB contiguous.
    const float* mbase = masks + ((long)(sb * 12) * F_FREQ + fc) * (T_TIME * 2)
                       + (lane << 2);
    const long MW_STRIDE = (long)F_FREQ * T_TIME * 2;

    const long tg0 = (long)(0 * B_BATCH + b) * C_CH * FT + rowBase;
    const long tg1 = (long)(1 * B_BATCH + b) * C_CH * FT + rowBase;

    float L0 = 0.0f, L1 = 0.0f;

    float4 qb[2][12];                   // double-buffered mask chunk
    #pragma unroll
    for (int mw = 0; mw < 12; ++mw)
        qb[0][mw] = *(const float4*)(mbase + (long)mw * MW_STRIDE);

    #pragma unroll
    for (int c = 0; c < 4; ++c) {       // 4 sequential 128-t chunks
        // ---- prefetch next chunk's masks (issue before consuming current) ----
        if (c < 3) {
            #pragma unroll
            for (int mw = 0; mw < 12; ++mw)
                qb[(c + 1) & 1][mw] =
                    *(const float4*)(mbase + (long)mw * MW_STRIDE + (c + 1) * 256);
        }

        const int t0 = c * 128 + (lane << 1);

        // ---- mix window loads: wv[m][k] = mix[m][f][tc+k], k=0..3 ----
        int tc = t0 - 1;
        tc = tc < 0 ? 0 : tc;
        tc = tc > (T_TIME - 4) ? (T_TIME - 4) : tc;

        float4u wr[M_MIC], wi[M_MIC];
        #pragma unroll
        for (int m = 0; m < M_MIC; ++m) {
            wr[m] = *(const float4u*)(mixr + mixSB + (long)m * FT + tc);
            wi[m] = *(const float4u*)(mixi + mixSB + (long)m * FT + tc);
        }

        // ---- target loads (channel 0), both candidate speakers ----
        const float2a t0r = *(const float2a*)(tgtr + tg0 + t0);
        const float2a t0i = *(const float2a*)(tgti + tg0 + t0);
        const float2a t1r = *(const float2a*)(tgtr + tg1 + t0);
        const float2a t1i = *(const float2a*)(tgti + tg1 + t0);

        // ---- boundary fixup (only live for c==0/lane==0 and c==3/lane==63) ----
        if (t0 == 0) {                 // loaded [0..3], want [pad,0,1,2]
            #pragma unroll
            for (int m = 0; m < M_MIC; ++m) {
                wr[m][3]=wr[m][2]; wr[m][2]=wr[m][1]; wr[m][1]=wr[m][0]; wr[m][0]=0.f;
                wi[m][3]=wi[m][2]; wi[m][2]=wi[m][1]; wi[m][1]=wi[m][0]; wi[m][0]=0.f;
            }
        } else if (t0 == T_TIME - 2) { // loaded [508..511], want [509,510,511,pad]
            #pragma unroll
            for (int m = 0; m < M_MIC; ++m) {
                wr[m][0]=wr[m][1]; wr[m][1]=wr[m][2]; wr[m][2]=wr[m][3]; wr[m][3]=0.f;
                wi[m][0]=wi[m][1]; wi[m][1]=wi[m][2]; wi[m][2]=wi[m][3]; wi[m][3]=0.f;
            }
        }

        // ---- complex MAC over (m,w) using current chunk buffer ----
        float or0 = 0.f, oi0 = 0.f, or1 = 0.f, oi1 = 0.f;
        #pragma unroll
        for (int m = 0; m < M_MIC; ++m) {
            #pragma unroll
            for (int w = 0; w < W_TAP; ++w) {
                const float4 qq = qb[c & 1][m * W_TAP + w];
                or0 += wr[m][w]     * qq.x - wi[m][w]     * qq.y;
                oi0 += wr[m][w]     * qq.y + wi[m][w]     * qq.x;
                or1 += wr[m][w + 1] * qq.z - wi[m][w + 1] * qq.w;
                oi1 += wr[m][w + 1] * qq.w + wi[m][w + 1] * qq.z;
            }
        }

        // ---- loss terms ----
        const float ao0 = sqrtf(or0 * or0 + oi0 * oi0);
        const float ao1 = sqrtf(or1 * or1 + oi1 * oi1);
        const float a00 = sqrtf(t0r[0] * t0r[0] + t0i[0] * t0i[0]);
        const float a01 = sqrtf(t0r[1] * t0r[1] + t0i[1] * t0i[1]);
        const float a10 = sqrtf(t1r[0] * t1r[0] + t1i[0] * t1i[0]);
        const float a11 = sqrtf(t1r[1] * t1r[1] + t1i[1] * t1i[1]);

        L0 += fabsf(t0r[0] - or0) + fabsf(t0i[0] - oi0) + fabsf(a00 - ao0)
            + fabsf(t0r[1] - or1) + fabsf(t0i[1] - oi1) + fabsf(a01 - ao1);
        L1 += fabsf(t1r[0] - or0) + fabsf(t1i[0] - oi0) + fabsf(a10 - ao0)
            + fabsf(t1r[1] - or1) + fabsf(t1i[1] - oi1) + fabsf(a11 - ao1);
    }

    L0 *= vf;
    L1 *= vf;

    // wave(64) shuffle reduction
    #pragma unroll
    for (int off = 32; off > 0; off >>= 1) {
        L0 += __shfl_down(L0, off, 64);
        L1 += __shfl_down(L1, off, 64);
    }
    __shared__ float s0[4], s1[4];
    if (lane == 0) { s0[wave] = L0; s1[wave] = L1; }
    __syncthreads();
    if (threadIdx.x == 0) {
        const int slot = blockIdx.y * NBLK_X + blockIdx.x;
        ws[slot * 2 + 0] = s0[0] + s0[1] + s0[2] + s0[3];
        ws[slot * 2 + 1] = s1[0] + s1[1] + s1[2] + s1[3];
    }
}

// One block, 256 threads: reduce NSLOT x 2 partials into L[so][st][b],
// then permutation-min. Kernel-boundary dependency makes partials coherent.
__global__ __launch_bounds__(256) void pit_final_kernel(
    const float* __restrict__ ws, float* __restrict__ out, int num_utts)
{
    float acc[16];                       // [so][st][b] = (so*2+st)*4+b
    #pragma unroll
    for (int i = 0; i < 16; ++i) acc[i] = 0.0f;

    for (int slot = threadIdx.x; slot < NSLOT; slot += 256) {
        const int sb = slot / NBLK_X;    // blockIdx.y of producer
        const int so = sb >> 2;
        const int b  = sb & 3;
        acc[((so * 2 + 0) << 2) + b] += ws[slot * 2 + 0];
        acc[((so * 2 + 1) << 2) + b] += ws[slot * 2 + 1];
    }

    __shared__ float red[16][4];
    const int wave = threadIdx.x >> 6;
    const int lane = threadIdx.x & 63;
    #pragma unroll
    for (int i = 0; i < 16; ++i) {
        float v = acc[i];
        #pragma unroll
        for (int off = 32; off > 0; off >>= 1) v += __shfl_down(v, off, 64);
        if (lane == 0) red[i][wave] = v;
    }
    __syncthreads();

    if (threadIdx.x == 0) {
        float L[16];
        #pragma unroll
        for (int i = 0; i < 16; ++i) L[i] = red[i][0] + red[i][1] + red[i][2] + red[i][3];
        float accu = 0.0f;
        for (int b = 0; b < B_BATCH; ++b) {
            // perm (0,1): L[0][0]+L[1][1];  perm (1,0): L[0][1]+L[1][0]
            const float pid = L[(0 * 2 + 0) * 4 + b] + L[(1 * 2 + 1) * 4 + b];
            const float psw = L[(0 * 2 + 1) * 4 + b] + L[(1 * 2 + 0) * 4 + b];
            const float sc0 = 3.0f * pid / (float)S_SPK;
            const float sc1 = 3.0f * psw / (float)S_SPK;
            accu += fminf(sc0, sc1);
        }
        out[0] = accu / (float)num_utts;
    }
}

extern "C" void kernel_launch(void* const* d_in, const int* in_sizes, int n_in,
                              void* d_out, int out_size, void* d_ws, size_t ws_size,
                              hipStream_t stream) {
    const float* masks = (const float*)d_in[0];
    const float* mixr  = (const float*)d_in[1];
    const float* mixi  = (const float*)d_in[2];
    const float* tgtr  = (const float*)d_in[3];
    const float* tgti  = (const float*)d_in[4];
    // input_sizes values are never used by the reference; only its length is.
    const int num_utts = in_sizes[5];

    float* ws  = (float*)d_ws;
    float* out = (float*)d_out;

    dim3 grid(NBLK_X, NBLK_Y);   // (65, 8)
    pit_main_kernel<<<grid, 256, 0, stream>>>(masks, mixr, mixi, tgtr, tgti, ws);

    pit_final_kernel<<<1, 256, 0, stream>>>(ws, out, num_utts);
}

// Round 8
// 196.094 us; speedup vs baseline: 1.0707x; 1.0707x over previous
//
#include <hip/hip_runtime.h>

// Problem constants (fixed by setup_inputs in the reference)
#define S_SPK 2
#define B_BATCH 4
#define M_MIC 4
#define W_TAP 3
#define F_FREQ 257
#define T_TIME 512
#define C_CH 4
#define FT (F_FREQ * T_TIME)      // 131584

#define NBLK (S_SPK * B_BATCH * F_FREQ)   // 2056 blocks: blk = sb*257 + f
#define NSLOT NBLK

// 8-byte float2 with 4-byte alignment (mix window loads are dword-aligned).
typedef float float2u __attribute__((ext_vector_type(2), aligned(4)));

// ws layout: float partial[NSLOT][2]
//
// Rounds 0-7 synthesis: every structure with >=8 waves/CU converges to
// ~2.2-2.6 TB/s demand BW -> per-CU in-flight cap (~64 lines) x ~800ns
// scattered-read latency. The copy ubench (6.3 TB/s) implies ~320ns under a
// DENSE sweeping frontier. This round maximizes address density:
//   block = (sb,f); wave mw in [0,12) reads its ENTIRE (m,w) mask T-row
//   (4 KB) in 4 contiguous coalesced float4 loads + its 2KB mix row;
//   partials reduced across the 12 waves via LDS. Only ~2 blocks/CU fit ->
//   ~1500 of 2056 blocks are dispatch-staggered, and blockIdx linear in
//   (sb,f) makes the chip-wide frontier sweep memory densely.

__global__ __launch_bounds__(768) void pit_main_kernel(
    const float* __restrict__ masks,   // [S,B,M,W,F,T,2]
    const float* __restrict__ mixr,    // [S,B,M,F,T]
    const float* __restrict__ mixi,    // [S,B,M,F,T]
    const float* __restrict__ tgtr,    // [S,B,C,F,T] (use c=0)
    const float* __restrict__ tgti,    // [S,B,C,F,T]
    float* __restrict__ ws)
{
    const int blk  = blockIdx.x;
    const int sb   = blk / F_FREQ;          // so*B + b  (0..7)
    const int f    = blk - sb * F_FREQ;     // 0..256
    const int b    = sb & 3;
    const int wv   = threadIdx.x >> 6;      // 0..11 = mw stream id
    const int lane = threadIdx.x & 63;
    const int m    = wv / 3;                // mic
    const int w    = wv - m * 3;            // tap

    // [mw][t*2+comp]: per-stream partial (or,oi) for all 512 t. 48 KB.
    __shared__ float part[12][1024];

    // ---- phase 1: each wave = one (m,w) stream --------------------------
    // masks row for (sb, m, w, f): 1024 floats, 4KB-aligned, contiguous.
    const float* mrow = masks + ((long)(sb * 12 + wv) * F_FREQ + f) * (T_TIME * 2);
    float4 q[4];
    #pragma unroll
    for (int c = 0; c < 4; ++c)             // 4 x 1KB coalesced (lane-stride 16B)
        q[c] = *(const float4*)(mrow + c * 256 + (lane << 2));

    // mix row m for this f: window value pair (mix[t0+w-1], mix[t0+w]).
    const float* mxr = mixr + ((long)(sb * M_MIC + m) * FT) + (long)f * T_TIME;
    const float* mxi = mixi + ((long)(sb * M_MIC + m) * FT) + (long)f * T_TIME;
    float2u xr[4], xi[4];
    #pragma unroll
    for (int c = 0; c < 4; ++c) {
        const int t0 = c * 128 + (lane << 1);
        int a = t0 + w - 1;                 // -1 .. 511
        a = a < 0 ? 0 : (a > 510 ? 510 : a);
        xr[c] = *(const float2u*)(mxr + a);
        xi[c] = *(const float2u*)(mxi + a);
    }
    // edge fixups (zero padding of the unfold)
    if (w == 0 && lane == 0) {   // c=0: t0=0, a=-1: loaded (m0,m1) want (0,m0)
        xr[0].y = xr[0].x; xr[0].x = 0.0f;
        xi[0].y = xi[0].x; xi[0].x = 0.0f;
    }
    if (w == 2 && lane == 63) {  // c=3: t0=510, a=511->510: loaded (m510,m511) want (m511,0)
        xr[3].x = xr[3].y; xr[3].y = 0.0f;
        xi[3].x = xi[3].y; xi[3].y = 0.0f;
    }

    // complex partial products -> LDS
    #pragma unroll
    for (int c = 0; c < 4; ++c) {
        float4 o;
        o.x = xr[c].x * q[c].x - xi[c].x * q[c].y;   // or(t0)
        o.y = xr[c].x * q[c].y + xi[c].x * q[c].x;   // oi(t0)
        o.z = xr[c].y * q[c].z - xi[c].y * q[c].w;   // or(t0+1)
        o.w = xr[c].y * q[c].w + xi[c].y * q[c].z;   // oi(t0+1)
        *(float4*)&part[wv][c * 256 + (lane << 2)] = o;
    }
    __syncthreads();

    // ---- phase 2: threads 0..511 each own one t -------------------------
    float L0 = 0.0f, L1 = 0.0f;
    if (threadIdx.x < 512) {
        const int t = threadIdx.x;
        float orr = 0.0f, oii = 0.0f;
        #pragma unroll
        for (int mw = 0; mw < 12; ++mw) {
            const float2u p = *(const float2u*)&part[mw][t * 2];
            orr += p.x;
            oii += p.y;
        }
        const long to = (long)f * T_TIME + t;
        const float t0r = tgtr[(long)(0 * B_BATCH + b) * C_CH * FT + to];
        const float t0i = tgti[(long)(0 * B_BATCH + b) * C_CH * FT + to];
        const float t1r = tgtr[(long)(1 * B_BATCH + b) * C_CH * FT + to];
        const float t1i = tgti[(long)(1 * B_BATCH + b) * C_CH * FT + to];

        const float ao = sqrtf(orr * orr + oii * oii);
        const float a0 = sqrtf(t0r * t0r + t0i * t0i);
        const float a1 = sqrtf(t1r * t1r + t1i * t1i);
        L0 = fabsf(t0r - orr) + fabsf(t0i - oii) + fabsf(a0 - ao);
        L1 = fabsf(t1r - orr) + fabsf(t1i - oii) + fabsf(a1 - ao);
    }

    // ---- block reduction (12 waves; waves 8..11 contribute 0) -----------
    #pragma unroll
    for (int off = 32; off > 0; off >>= 1) {
        L0 += __shfl_down(L0, off, 64);
        L1 += __shfl_down(L1, off, 64);
    }
    __shared__ float s0[12], s1[12];
    if (lane == 0) { s0[wv] = L0; s1[wv] = L1; }
    __syncthreads();
    if (threadIdx.x == 0) {
        float a = 0.0f, c = 0.0f;
        #pragma unroll
        for (int i = 0; i < 12; ++i) { a += s0[i]; c += s1[i]; }
        ws[blk * 2 + 0] = a;
        ws[blk * 2 + 1] = c;
    }
}

// One block, 256 threads: reduce NSLOT x 2 partials into L[so][st][b],
// then permutation-min. Kernel-boundary dependency makes partials coherent.
__global__ __launch_bounds__(256) void pit_final_kernel(
    const float* __restrict__ ws, float* __restrict__ out, int num_utts)
{
    float acc[16];                       // [so][st][b] = (so*2+st)*4+b
    #pragma unroll
    for (int i = 0; i < 16; ++i) acc[i] = 0.0f;

    for (int slot = threadIdx.x; slot < NSLOT; slot += 256) {
        const int sb = slot / F_FREQ;    // producer's sb
        const int so = sb >> 2;
        const int b  = sb & 3;
        acc[((so * 2 + 0) << 2) + b] += ws[slot * 2 + 0];
        acc[((so * 2 + 1) << 2) + b] += ws[slot * 2 + 1];
    }

    __shared__ float red[16][4];
    const int wave = threadIdx.x >> 6;
    const int lane = threadIdx.x & 63;
    #pragma unroll
    for (int i = 0; i < 16; ++i) {
        float v = acc[i];
        #pragma unroll
        for (int off = 32; off > 0; off >>= 1) v += __shfl_down(v, off, 64);
        if (lane == 0) red[i][wave] = v;
    }
    __syncthreads();

    if (threadIdx.x == 0) {
        float L[16];
        #pragma unroll
        for (int i = 0; i < 16; ++i) L[i] = red[i][0] + red[i][1] + red[i][2] + red[i][3];
        float accu = 0.0f;
        for (int b = 0; b < B_BATCH; ++b) {
            // perm (0,1): L[0][0]+L[1][1];  perm (1,0): L[0][1]+L[1][0]
            const float pid = L[(0 * 2 + 0) * 4 + b] + L[(1 * 2 + 1) * 4 + b];
            const float psw = L[(0 * 2 + 1) * 4 + b] + L[(1 * 2 + 0) * 4 + b];
            const float sc0 = 3.0f * pid / (float)S_SPK;
            const float sc1 = 3.0f * psw / (float)S_SPK;
            accu += fminf(sc0, sc1);
        }
        out[0] = accu / (float)num_utts;
    }
}

extern "C" void kernel_launch(void* const* d_in, const int* in_sizes, int n_in,
                              void* d_out, int out_size, void* d_ws, size_t ws_size,
                              hipStream_t stream) {
    const float* masks = (const float*)d_in[0];
    const float* mixr  = (const float*)d_in[1];
    const float* mixi  = (const float*)d_in[2];
    const float* tgtr  = (const float*)d_in[3];
    const float* tgti  = (const float*)d_in[4];
    // input_sizes values are never used by the reference; only its length is.
    const int num_utts = in_sizes[5];

    float* ws  = (float*)d_ws;
    float* out = (float*)d_out;

    pit_main_kernel<<<NBLK, 768, 0, stream>>>(masks, mixr, mixi, tgtr, tgti, ws);

    pit_final_kernel<<<1, 256, 0, stream>>>(ws, out, num_utts);
}

// Round 10
// 190.584 us; speedup vs baseline: 1.1016x; 1.0289x over previous
//
#include <hip/hip_runtime.h>

// Problem constants (fixed by setup_inputs in the reference)
#define S_SPK 2
#define B_BATCH 4
#define M_MIC 4
#define W_TAP 3
#define F_FREQ 257
#define T_TIME 512
#define C_CH 4
#define FT (F_FREQ * T_TIME)      // 131584

#define NBLK (S_SPK * B_BATCH * F_FREQ)   // 2056 blocks: blk = sb*257 + f
#define NSLOT NBLK

// clang ext_vector types: __builtin_nontemporal_load requires scalar /
// ext_vector pointee (HIP_vector_type float4 is rejected).
typedef float float4e __attribute__((ext_vector_type(4)));           // 16B aligned
typedef float float2u __attribute__((ext_vector_type(2), aligned(4)));

// ws layout: float partial[NSLOT][2]
//
// Round 0-8 synthesis: five structurally diverse mains converge to ~2.3-2.9
// TB/s demand-read BW (write-only fill: 6.9 TB/s). Geometry is exhausted;
// this round changes load POLICY: all input streams are single-use per
// iteration, so read them nontemporally (nt bit -> no L1/L2 allocation,
// lighter miss path, less MSHR dwell). Structure = round 8 (best):
//   block = (sb,f); wave mw in [0,12) reads its (m,w) mask T-row (4 KB) in
//   4 contiguous coalesced float4 loads + its mix row; partials via LDS;
//   phase-2 target loads hoisted above the barrier to hide their latency.

__global__ __launch_bounds__(768) void pit_main_kernel(
    const float* __restrict__ masks,   // [S,B,M,W,F,T,2]
    const float* __restrict__ mixr,    // [S,B,M,F,T]
    const float* __restrict__ mixi,    // [S,B,M,F,T]
    const float* __restrict__ tgtr,    // [S,B,C,F,T] (use c=0)
    const float* __restrict__ tgti,    // [S,B,C,F,T]
    float* __restrict__ ws)
{
    const int blk  = blockIdx.x;
    const int sb   = blk / F_FREQ;          // so*B + b  (0..7)
    const int f    = blk - sb * F_FREQ;     // 0..256
    const int b    = sb & 3;
    const int wv   = threadIdx.x >> 6;      // 0..11 = mw stream id
    const int lane = threadIdx.x & 63;
    const int m    = wv / 3;                // mic
    const int w    = wv - m * 3;            // tap

    // [mw][t*2+comp]: per-stream partial (or,oi) for all 512 t. 48 KB.
    __shared__ float part[12][1024];

    // ---- phase 1: each wave = one (m,w) stream --------------------------
    // masks row for (sb, m, w, f): 1024 floats, 4KB-aligned, contiguous.
    const float* mrow = masks + ((long)(sb * 12 + wv) * F_FREQ + f) * (T_TIME * 2);
    float4e q[4];
    #pragma unroll
    for (int c = 0; c < 4; ++c)             // 4 x 1KB coalesced (lane-stride 16B)
        q[c] = __builtin_nontemporal_load((const float4e*)(mrow + c * 256 + (lane << 2)));

    // mix row m for this f: window value pair (mix[t0+w-1], mix[t0+w]).
    const float* mxr = mixr + ((long)(sb * M_MIC + m) * FT) + (long)f * T_TIME;
    const float* mxi = mixi + ((long)(sb * M_MIC + m) * FT) + (long)f * T_TIME;
    float2u xr[4], xi[4];
    #pragma unroll
    for (int c = 0; c < 4; ++c) {
        const int t0 = c * 128 + (lane << 1);
        int a = t0 + w - 1;                 // -1 .. 511
        a = a < 0 ? 0 : (a > 510 ? 510 : a);
        xr[c] = __builtin_nontemporal_load((const float2u*)(mxr + a));
        xi[c] = __builtin_nontemporal_load((const float2u*)(mxi + a));
    }

    // ---- hoisted phase-2 target loads (independent of LDS; latency hides
    // under the products + barrier) ---------------------------------------
    float t0r = 0.f, t0i = 0.f, t1r = 0.f, t1i = 0.f;
    if (threadIdx.x < 512) {
        const long to = (long)f * T_TIME + threadIdx.x;
        t0r = __builtin_nontemporal_load(tgtr + (long)(0 * B_BATCH + b) * C_CH * FT + to);
        t0i = __builtin_nontemporal_load(tgti + (long)(0 * B_BATCH + b) * C_CH * FT + to);
        t1r = __builtin_nontemporal_load(tgtr + (long)(1 * B_BATCH + b) * C_CH * FT + to);
        t1i = __builtin_nontemporal_load(tgti + (long)(1 * B_BATCH + b) * C_CH * FT + to);
    }

    // edge fixups (zero padding of the unfold)
    if (w == 0 && lane == 0) {   // c=0: t0=0, a=-1: loaded (m0,m1) want (0,m0)
        xr[0].y = xr[0].x; xr[0].x = 0.0f;
        xi[0].y = xi[0].x; xi[0].x = 0.0f;
    }
    if (w == 2 && lane == 63) {  // c=3: t0=510, a=511->510: loaded (m510,m511) want (m511,0)
        xr[3].x = xr[3].y; xr[3].y = 0.0f;
        xi[3].x = xi[3].y; xi[3].y = 0.0f;
    }

    // complex partial products -> LDS
    #pragma unroll
    for (int c = 0; c < 4; ++c) {
        float4e o;
        o.x = xr[c].x * q[c].x - xi[c].x * q[c].y;   // or(t0)
        o.y = xr[c].x * q[c].y + xi[c].x * q[c].x;   // oi(t0)
        o.z = xr[c].y * q[c].z - xi[c].y * q[c].w;   // or(t0+1)
        o.w = xr[c].y * q[c].w + xi[c].y * q[c].z;   // oi(t0+1)
        *(float4e*)&part[wv][c * 256 + (lane << 2)] = o;
    }
    __syncthreads();

    // ---- phase 2: threads 0..511 each own one t -------------------------
    float L0 = 0.0f, L1 = 0.0f;
    if (threadIdx.x < 512) {
        const int t = threadIdx.x;
        float orr = 0.0f, oii = 0.0f;
        #pragma unroll
        for (int mw = 0; mw < 12; ++mw) {
            const float2u p = *(const float2u*)&part[mw][t * 2];
            orr += p.x;
            oii += p.y;
        }
        const float ao = sqrtf(orr * orr + oii * oii);
        const float a0 = sqrtf(t0r * t0r + t0i * t0i);
        const float a1 = sqrtf(t1r * t1r + t1i * t1i);
        L0 = fabsf(t0r - orr) + fabsf(t0i - oii) + fabsf(a0 - ao);
        L1 = fabsf(t1r - orr) + fabsf(t1i - oii) + fabsf(a1 - ao);
    }

    // ---- block reduction (12 waves; waves 8..11 contribute 0) -----------
    #pragma unroll
    for (int off = 32; off > 0; off >>= 1) {
        L0 += __shfl_down(L0, off, 64);
        L1 += __shfl_down(L1, off, 64);
    }
    __shared__ float s0[12], s1[12];
    if (lane == 0) { s0[wv] = L0; s1[wv] = L1; }
    __syncthreads();
    if (threadIdx.x == 0) {
        float a = 0.0f, c = 0.0f;
        #pragma unroll
        for (int i = 0; i < 12; ++i) { a += s0[i]; c += s1[i]; }
        ws[blk * 2 + 0] = a;
        ws[blk * 2 + 1] = c;
    }
}

// One block, 256 threads: reduce NSLOT x 2 partials into L[so][st][b],
// then permutation-min. Kernel-boundary dependency makes partials coherent.
__global__ __launch_bounds__(256) void pit_final_kernel(
    const float* __restrict__ ws, float* __restrict__ out, int num_utts)
{
    float acc[16];                       // [so][st][b] = (so*2+st)*4+b
    #pragma unroll
    for (int i = 0; i < 16; ++i) acc[i] = 0.0f;

    for (int slot = threadIdx.x; slot < NSLOT; slot += 256) {
        const int sb = slot / F_FREQ;    // producer's sb
        const int so = sb >> 2;
        const int b  = sb & 3;
        acc[((so * 2 + 0) << 2) + b] += ws[slot * 2 + 0];
        acc[((so * 2 + 1) << 2) + b] += ws[slot * 2 + 1];
    }

    __shared__ float red[16][4];
    const int wave = threadIdx.x >> 6;
    const int lane = threadIdx.x & 63;
    #pragma unroll
    for (int i = 0; i < 16; ++i) {
        float v = acc[i];
        #pragma unroll
        for (int off = 32; off > 0; off >>= 1) v += __shfl_down(v, off, 64);
        if (lane == 0) red[i][wave] = v;
    }
    __syncthreads();

    if (threadIdx.x == 0) {
        float L[16];
        #pragma unroll
        for (int i = 0; i < 16; ++i) L[i] = red[i][0] + red[i][1] + red[i][2] + red[i][3];
        float accu = 0.0f;
        for (int b = 0; b < B_BATCH; ++b) {
            // perm (0,1): L[0][0]+L[1][1];  perm (1,0): L[0][1]+L[1][0]
            const float pid = L[(0 * 2 + 0) * 4 + b] + L[(1 * 2 + 1) * 4 + b];
            const float psw = L[(0 * 2 + 1) * 4 + b] + L[(1 * 2 + 0) * 4 + b];
            const float sc0 = 3.0f * pid / (float)S_SPK;
            const float sc1 = 3.0f * psw / (float)S_SPK;
            accu += fminf(sc0, sc1);
        }
        out[0] = accu / (float)num_utts;
    }
}

extern "C" void kernel_launch(void* const* d_in, const int* in_sizes, int n_in,
                              void* d_out, int out_size, void* d_ws, size_t ws_size,
                              hipStream_t stream) {
    const float* masks = (const float*)d_in[0];
    const float* mixr  = (const float*)d_in[1];
    const float* mixi  = (const float*)d_in[2];
    const float* tgtr  = (const float*)d_in[3];
    const float* tgti  = (const float*)d_in[4];
    // input_sizes values are never used by the reference; only its length is.
    const int num_utts = in_sizes[5];

    float* ws  = (float*)d_ws;
    float* out = (float*)d_out;

    pit_main_kernel<<<NBLK, 768, 0, stream>>>(masks, mixr, mixi, tgtr, tgti, ws);

    pit_final_kernel<<<1, 256, 0, stream>>>(ws, out, num_utts);
}